// Round 9
// baseline (216.943 us; speedup 1.0000x reference)
//
#include <hip/hip_runtime.h>

static constexpr int   KBINS = 16;
static constexpr float TB    = 3.0f;
static constexpr float MIN_W = 0.001f;
static constexpr float MIN_H = 0.001f;
static constexpr float MIN_D = 0.001f;
static constexpr int   PPL   = 47;     // floats per layer (3*16-1)
static constexpr int   REC_F4 = 47;    // float4 chunks per element record

__device__ __forceinline__ float softplusf(float v) {
  return fmaxf(v, 0.0f) + __logf(1.0f + __expf(-fabsf(v)));
}

template<int F0, int N>
__device__ __forceinline__ void extractAbs(const float4* ch, float* a) {
#pragma unroll
  for (int k = 0; k < N; ++k) {
    const int f = F0 + k;
    const float4 q = ch[f >> 2];
    const int c = f & 3;
    a[k] = (c == 0) ? q.x : (c == 1) ? q.y : (c == 2) ? q.z : q.w;
  }
}

template<int LI>
__device__ __forceinline__ void computeLayer(const float4* ch, float& x, float& ldsum) {
  const float xc = fminf(fmaxf(x, -TB), TB);

  float uw[KBINS];
  extractAbs<LI * PPL, KBINS>(ch, uw);
  float s = 0.0f;
#pragma unroll
  for (int k = 0; k < KBINS; ++k) { uw[k] = __expf(uw[k]); s += uw[k]; }
  const float csw = (1.0f - KBINS * MIN_W) / s;

  float cum = 0.0f, ek = -TB;
  float xk = -TB, xk1 = TB;
  int idx = 0;
#pragma unroll
  for (int k = 0; k < KBINS; ++k) {
    cum += fmaf(uw[k], csw, MIN_W);
    const float ek1 = (k == KBINS - 1) ? TB : fmaf(2.0f * TB, cum, -TB);
    if (xc >= ek) { idx = k; xk = ek; xk1 = ek1; }
    ek = ek1;
  }
  const float wk = xk1 - xk;

  float uh[KBINS];
  extractAbs<LI * PPL + KBINS, KBINS>(ch, uh);
  s = 0.0f;
#pragma unroll
  for (int k = 0; k < KBINS; ++k) { uh[k] = __expf(uh[k]); s += uh[k]; }
  const float csh = (1.0f - KBINS * MIN_H) / s;

  cum = 0.0f; ek = -TB;
  float yk = -TB, yk1 = TB;
#pragma unroll
  for (int k = 0; k < KBINS; ++k) {
    cum += fmaf(uh[k], csh, MIN_H);
    const float ek1 = (k == KBINS - 1) ? TB : fmaf(2.0f * TB, cum, -TB);
    if (k == idx) { yk = ek; yk1 = ek1; }
    ek = ek1;
  }
  const float hk = yk1 - yk;

  float ud[KBINS - 1];
  extractAbs<LI * PPL + 2 * KBINS, KBINS - 1>(ch, ud);
  float udk = 0.0f, udk1 = 0.0f;
#pragma unroll
  for (int j = 0; j < KBINS - 1; ++j) {
    if (j == idx - 1) udk  = ud[j];
    if (j == idx)     udk1 = ud[j];
  }
  const float dk  = (idx == 0)         ? 1.0f : MIN_D + softplusf(udk);
  const float dk1 = (idx == KBINS - 1) ? 1.0f : MIN_D + softplusf(udk1);

  const float rw    = 1.0f / wk;
  const float delta = hk * rw;
  const float theta = (xc - xk) * rw;
  const float omt   = 1.0f - theta;
  const float t1m   = theta * omt;
  const float denom = delta + (dk + dk1 - 2.0f * delta) * t1m;
  const float y     = yk + hk * (delta * theta * theta + dk * t1m) / denom;
  const float dnum  = (delta * delta) *
                      (dk1 * theta * theta + 2.0f * delta * t1m + dk * omt * omt);
  const float ld    = __logf(dnum) - 2.0f * __logf(denom);

  const bool inside = (x >= -TB) && (x <= TB);
  x      = inside ? y : x;
  ldsum += inside ? ld : 0.0f;
}

// ---------------- PROBE: pure delivery of the scattered burst ----------------
// Same grid / launch bounds / access pattern as the real kernel, zero compute
// beyond a cheap fold (consumes all 4 components so the dwordx4 loads can't be
// narrowed or DCE'd), no stores. Its marginal time = delivery time of the
// scattered pattern at 8 waves/CU.
__global__ __launch_bounds__(256, 2) void nsf_probe(
    const float* __restrict__ params, const float* __restrict__ xin) {
  const int e = blockIdx.x * 256 + threadIdx.x;
  const float4* p4 = reinterpret_cast<const float4*>(params) + (size_t)e * REC_F4;

  float4 ch[REC_F4];
#pragma unroll
  for (int j = 0; j < REC_F4; ++j) ch[j] = p4[j];   // identical 47-deep burst
  float x = xin[e];

  float s = x;                                       // fold after all issues
#pragma unroll
  for (int j = 0; j < REC_F4; ++j)
    s += ch[j].x + ch[j].y + ch[j].z + ch[j].w;
  asm volatile("" :: "v"(s));                        // zero-cost keepalive
}

// ---------------- PRODUCTION: byte-identical to R8 (85.3 us) ----------------
__global__ __launch_bounds__(256, 2) void nsf_flow_burst2(
    const float* __restrict__ params, const float* __restrict__ xin,
    float* __restrict__ yout, float* __restrict__ logdet, int epb) {
  const int e = blockIdx.x * 256 + threadIdx.x;
  const float4* p4 = reinterpret_cast<const float4*>(params) + (size_t)e * REC_F4;

  float x = xin[e];
  __builtin_amdgcn_sched_barrier(0);

  float4 ch[REC_F4];
#pragma unroll
  for (int j = 0; j < REC_F4; ++j) ch[j] = p4[j];

  float ldsum = 0.0f;
  computeLayer<0>(ch, x, ldsum);
  computeLayer<1>(ch, x, ldsum);
  computeLayer<2>(ch, x, ldsum);
  computeLayer<3>(ch, x, ldsum);

  yout[e] = x;

  float v = ldsum;
#pragma unroll
  for (int o = 32; o > 0; o >>= 1) v += __shfl_xor(v, o, 64);
  __shared__ float red[4];
  const int wid = threadIdx.x >> 6;
  if ((threadIdx.x & 63) == 0) red[wid] = v;
  __syncthreads();
  if (threadIdx.x == 0) {
    const int b = e / epb;
    atomicAdd(&logdet[b], red[0] + red[1] + red[2] + red[3]);
  }
}

extern "C" void kernel_launch(void* const* d_in, const int* in_sizes, int n_in,
                              void* d_out, int out_size, void* d_ws, size_t ws_size,
                              hipStream_t stream) {
  const float* params = (const float*)d_in[0];
  const float* x      = (const float*)d_in[1];
  const int n   = in_sizes[1];        // 524288 elements
  const int nb  = out_size - n;       // 32 batches
  const int epb = n / nb;             // 16384 elements per batch
  float* y      = (float*)d_out;
  float* logdet = y + n;

  hipMemsetAsync(logdet, 0, nb * sizeof(float), stream);
  nsf_probe<<<dim3(n / 256), dim3(256), 0, stream>>>(params, x);          // P
  nsf_flow_burst2<<<dim3(n / 256), dim3(256), 0, stream>>>(params, x, y,  // A
                                                           logdet, epb);
}

// Round 10
// 122.963 us; speedup vs baseline: 1.7643x; 1.7643x over previous
//
#include <hip/hip_runtime.h>

static constexpr int   KBINS = 16;
static constexpr float TB    = 3.0f;
static constexpr float MIN_W = 0.001f;
static constexpr float MIN_H = 0.001f;
static constexpr float MIN_D = 0.001f;
static constexpr int   PPL   = 47;     // floats per layer (3*16-1)

__device__ __forceinline__ float softplusf(float v) {
  return fmaxf(v, 0.0f) + __logf(1.0f + __expf(-fabsf(v)));
}

__device__ __forceinline__ float comp(const float4& q, int t) {
  return (t == 0) ? q.x : (t == 1) ? q.y : (t == 2) ? q.z : q.w;
}

// Inclusive->exclusive scan + total across the 4 lanes of a quad.
__device__ __forceinline__ void quadScan(float v, int cq, float& excl, float& tot) {
  float inc = v;
  float u1 = __shfl_up(inc, 1, 4); inc += (cq >= 1) ? u1 : 0.0f;
  float u2 = __shfl_up(inc, 2, 4); inc += (cq >= 2) ? u2 : 0.0f;
  excl = inc - v;
  tot  = __shfl(inc, 3, 4);
}

// ---- widths window [GW0, GW0+16): softmax + edge build + containing-bin search.
// Lane cq holds chunks c,c+4,.. of the record; window spans register slots S0
// (and S1 = S0+1 when unaligned). rel = bin index = global float idx - GW0.
template<int GW0, int S0, int S1>
__device__ __forceinline__ void widthSearch(const float4* ch, int cq, float xc,
                                            int& idx, float& xk, float& wk) {
  constexpr bool TWO = (S1 != S0);
  const int c4 = cq * 4;
  float eA[4], eB[4];
  float sA = 0.0f, sB = 0.0f;
#pragma unroll
  for (int t = 0; t < 4; ++t) {
    const int rel = c4 + (16 * S0 + t - GW0);
    const bool in = (rel >= 0) && (rel < 16);
    const float e = in ? __expf(comp(ch[S0], t)) : 0.0f;
    eA[t] = e; sA += e;
  }
  if constexpr (TWO) {
#pragma unroll
    for (int t = 0; t < 4; ++t) {
      const int rel = c4 + (16 * S1 + t - GW0);
      const bool in = (rel >= 0) && (rel < 16);
      const float e = in ? __expf(comp(ch[S1], t)) : 0.0f;
      eB[t] = e; sB += e;
    }
  }
  float bA, tA, bB = 0.0f, tBt = 0.0f;
  quadScan(sA, cq, bA, tA);
  if constexpr (TWO) quadScan(sB, cq, bB, tBt);
  const float csw = (1.0f - KBINS * MIN_W) / (tA + tBt);

  int   brel = -1;
  float bxk = 0.0f, bwk = 1.0f;
  float cum = bA;
#pragma unroll
  for (int t = 0; t < 4; ++t) {
    const int rel = c4 + (16 * S0 + t - GW0);
    const bool in = (rel >= 0) && (rel < 16);
    const float cumL = cum; cum += eA[t];
    const float eL = (rel == 0)  ? -TB : fmaf(6.0f, fmaf(csw, cumL, MIN_W * rel), -TB);
    const float eR = (rel == 15) ?  TB : fmaf(6.0f, fmaf(csw, cum, MIN_W * (rel + 1)), -TB);
    const bool val = in && (xc >= eL);
    brel = val ? rel : brel;
    bxk  = val ? eL  : bxk;
    bwk  = val ? (eR - eL) : bwk;
  }
  if constexpr (TWO) {
    cum = tA + bB;
#pragma unroll
    for (int t = 0; t < 4; ++t) {
      const int rel = c4 + (16 * S1 + t - GW0);
      const bool in = (rel >= 0) && (rel < 16);
      const float cumL = cum; cum += eB[t];
      const float eL = (rel == 0)  ? -TB : fmaf(6.0f, fmaf(csw, cumL, MIN_W * rel), -TB);
      const float eR = (rel == 15) ?  TB : fmaf(6.0f, fmaf(csw, cum, MIN_W * (rel + 1)), -TB);
      const bool val = in && (xc >= eL);
      brel = val ? rel : brel;
      bxk  = val ? eL  : bxk;
      bwk  = val ? (eR - eL) : bwk;
    }
  }
#pragma unroll
  for (int d = 1; d <= 2; d <<= 1) {      // quad max-by-rel combine
    const int   orel = __shfl_xor(brel, d);
    const float oxk  = __shfl_xor(bxk, d);
    const float owk  = __shfl_xor(bwk, d);
    const bool take = orel > brel;
    brel = take ? orel : brel;
    bxk  = take ? oxk  : bxk;
    bwk  = take ? owk  : bwk;
  }
  idx = brel; xk = bxk; wk = bwk;
}

// ---- heights window: softmax + one-hot gather of (yk, yk+1) at idx.
template<int GW0, int S0, int S1>
__device__ __forceinline__ void heightGather(const float4* ch, int cq, int idx,
                                             float& yk, float& hk) {
  constexpr bool TWO = (S1 != S0);
  const int c4 = cq * 4;
  float eA[4], eB[4];
  float sA = 0.0f, sB = 0.0f;
#pragma unroll
  for (int t = 0; t < 4; ++t) {
    const int rel = c4 + (16 * S0 + t - GW0);
    const bool in = (rel >= 0) && (rel < 16);
    const float e = in ? __expf(comp(ch[S0], t)) : 0.0f;
    eA[t] = e; sA += e;
  }
  if constexpr (TWO) {
#pragma unroll
    for (int t = 0; t < 4; ++t) {
      const int rel = c4 + (16 * S1 + t - GW0);
      const bool in = (rel >= 0) && (rel < 16);
      const float e = in ? __expf(comp(ch[S1], t)) : 0.0f;
      eB[t] = e; sB += e;
    }
  }
  float bA, tA, bB = 0.0f, tBt = 0.0f;
  quadScan(sA, cq, bA, tA);
  if constexpr (TWO) quadScan(sB, cq, bB, tBt);
  const float csh = (1.0f - KBINS * MIN_H) / (tA + tBt);

  float ykc = 0.0f, yk1c = 0.0f;
  float cum = bA;
#pragma unroll
  for (int t = 0; t < 4; ++t) {
    const int rel = c4 + (16 * S0 + t - GW0);
    const bool in = (rel >= 0) && (rel < 16);
    const float cumL = cum; cum += eA[t];
    const float eL = (rel == 0)  ? -TB : fmaf(6.0f, fmaf(csh, cumL, MIN_H * rel), -TB);
    const float eR = (rel == 15) ?  TB : fmaf(6.0f, fmaf(csh, cum, MIN_H * (rel + 1)), -TB);
    const bool match = in && (rel == idx);
    ykc  += match ? eL : 0.0f;
    yk1c += match ? eR : 0.0f;
  }
  if constexpr (TWO) {
    cum = tA + bB;
#pragma unroll
    for (int t = 0; t < 4; ++t) {
      const int rel = c4 + (16 * S1 + t - GW0);
      const bool in = (rel >= 0) && (rel < 16);
      const float cumL = cum; cum += eB[t];
      const float eL = (rel == 0)  ? -TB : fmaf(6.0f, fmaf(csh, cumL, MIN_H * rel), -TB);
      const float eR = (rel == 15) ?  TB : fmaf(6.0f, fmaf(csh, cum, MIN_H * (rel + 1)), -TB);
      const bool match = in && (rel == idx);
      ykc  += match ? eL : 0.0f;
      yk1c += match ? eR : 0.0f;
    }
  }
  ykc  += __shfl_xor(ykc, 1);  ykc  += __shfl_xor(ykc, 2);
  yk1c += __shfl_xor(yk1c, 1); yk1c += __shfl_xor(yk1c, 2);
  yk = ykc; hk = yk1c - ykc;
}

// ---- derivatives window [GW0, GW0+15): one-hot gather of ud[idx-1], ud[idx].
template<int GW0, int S0, int S1>
__device__ __forceinline__ void derivGather(const float4* ch, int cq, int idx,
                                            float& dk, float& dk1) {
  const int c4 = cq * 4;
  float a0 = 0.0f, a1 = 0.0f;
#pragma unroll
  for (int t = 0; t < 4; ++t) {
    const int rel = c4 + (16 * S0 + t - GW0);
    const bool in = (rel >= 0) && (rel < 15);
    const float v = comp(ch[S0], t);
    a0 += (in && (rel == idx - 1)) ? v : 0.0f;
    a1 += (in && (rel == idx))     ? v : 0.0f;
  }
  if constexpr (S1 != S0) {
#pragma unroll
    for (int t = 0; t < 4; ++t) {
      const int rel = c4 + (16 * S1 + t - GW0);
      const bool in = (rel >= 0) && (rel < 15);
      const float v = comp(ch[S1], t);
      a0 += (in && (rel == idx - 1)) ? v : 0.0f;
      a1 += (in && (rel == idx))     ? v : 0.0f;
    }
  }
  a0 += __shfl_xor(a0, 1); a0 += __shfl_xor(a0, 2);
  a1 += __shfl_xor(a1, 1); a1 += __shfl_xor(a1, 2);
  dk  = (idx == 0)         ? 1.0f : MIN_D + softplusf(a0);
  dk1 = (idx == KBINS - 1) ? 1.0f : MIN_D + softplusf(a1);
}

template<int LI>
__device__ __forceinline__ void layer(const float4* ch, int cq, float& x, float& ldsum) {
  constexpr int F0  = LI * PPL;
  constexpr int SW0 = F0 >> 4,        SW1 = (F0 + 15) >> 4;
  constexpr int SH0 = (F0 + 16) >> 4, SH1 = (F0 + 31) >> 4;
  constexpr int SD0 = (F0 + 32) >> 4, SD1 = (F0 + 46) >> 4;

  const float xc = fminf(fmaxf(x, -TB), TB);

  int idx; float xk, wk;
  widthSearch<F0, SW0, SW1>(ch, cq, xc, idx, xk, wk);
  float yk, hk;
  heightGather<F0 + 16, SH0, SH1>(ch, cq, idx, yk, hk);
  float dk, dk1;
  derivGather<F0 + 32, SD0, SD1>(ch, cq, idx, dk, dk1);

  const float rw    = 1.0f / wk;
  const float delta = hk * rw;
  const float theta = (xc - xk) * rw;
  const float omt   = 1.0f - theta;
  const float t1m   = theta * omt;
  const float denom = delta + (dk + dk1 - 2.0f * delta) * t1m;
  const float y     = yk + hk * (delta * theta * theta + dk * t1m) / denom;
  const float dnum  = (delta * delta) *
                      (dk1 * theta * theta + 2.0f * delta * t1m + dk * omt * omt);
  const float ld    = __logf(dnum) - 2.0f * __logf(denom);

  const bool inside = (x >= -TB) && (x <= TB);
  x      = inside ? y : x;
  ldsum += inside ? ld : 0.0f;
}

// 4 lanes cooperate on one record: lane cq loads chunks cq, cq+4, ..., so each
// load instruction reads 64 contiguous bytes per quad -> 16 cache lines/instr
// (the coalesced minimum; the 1-elem/thread burst touched 64 lines/instr).
// Record stays register-resident at 48 VGPR/lane.
__global__ __launch_bounds__(256, 3) void nsf_quad(
    const float* __restrict__ params, const float* __restrict__ xin,
    float* __restrict__ yout, float* __restrict__ logdet, int bpb) {
  const int l  = threadIdx.x;
  const int cq = l & 3;
  const int r  = blockIdx.x * 64 + (l >> 2);
  const float4* p4 = reinterpret_cast<const float4*>(params) + (size_t)r * PPL;

  float x = xin[r];
  float4 ch[12];
#pragma unroll
  for (int i = 0; i < 11; ++i) ch[i] = p4[cq + 4 * i];
  {
    int cc = cq + 44; cc = (cc > 46) ? 46 : cc;   // lane 3 slot 11 unused; clamp in-bounds
    ch[11] = p4[cc];
  }

  float ldsum = 0.0f;
  layer<0>(ch, cq, x, ldsum);
  layer<1>(ch, cq, x, ldsum);
  layer<2>(ch, cq, x, ldsum);
  layer<3>(ch, cq, x, ldsum);

  if (cq == 0) yout[r] = x;

  float v = (cq == 0) ? ldsum : 0.0f;     // quad lanes hold identical ld; count once
#pragma unroll
  for (int o = 32; o > 0; o >>= 1) v += __shfl_xor(v, o, 64);
  __shared__ float red[4];
  const int wid = l >> 6;
  if ((l & 63) == 0) red[wid] = v;
  __syncthreads();
  if (l == 0) atomicAdd(&logdet[blockIdx.x / bpb], red[0] + red[1] + red[2] + red[3]);
}

extern "C" void kernel_launch(void* const* d_in, const int* in_sizes, int n_in,
                              void* d_out, int out_size, void* d_ws, size_t ws_size,
                              hipStream_t stream) {
  const float* params = (const float*)d_in[0];
  const float* x      = (const float*)d_in[1];
  const int n   = in_sizes[1];        // 524288 elements
  const int nb  = out_size - n;       // 32 batches
  const int epb = n / nb;             // 16384 elements per batch
  const int blocks = n / 64;          // 64 records per 256-thread block
  const int bpb    = epb / 64;        // blocks per batch (256)
  float* y      = (float*)d_out;
  float* logdet = y + n;

  hipMemsetAsync(logdet, 0, nb * sizeof(float), stream);
  nsf_quad<<<dim3(blocks), dim3(256), 0, stream>>>(params, x, y, logdet, bpb);
}

// Round 11
// 84.807 us; speedup vs baseline: 2.5581x; 1.4499x over previous
//
#include <hip/hip_runtime.h>

static constexpr int   KBINS = 16;
static constexpr float TB    = 3.0f;
static constexpr float MIN_W = 0.001f;
static constexpr float MIN_H = 0.001f;
static constexpr float MIN_D = 0.001f;
static constexpr int   PPL   = 47;     // floats per layer (3*16-1)
static constexpr int   REC_F4 = 47;    // float4 chunks per element record

__device__ __forceinline__ float softplusf(float v) {
  return fmaxf(v, 0.0f) + __logf(1.0f + __expf(-fabsf(v)));
}

template<int F0, int N>
__device__ __forceinline__ void extractAbs(const float4* ch, float* a) {
#pragma unroll
  for (int k = 0; k < N; ++k) {
    const int f = F0 + k;
    const float4 q = ch[f >> 2];
    const int c = f & 3;
    a[k] = (c == 0) ? q.x : (c == 1) ? q.y : (c == 2) ? q.z : q.w;
  }
}

template<int LI>
__device__ __forceinline__ void computeLayer(const float4* ch, float& x, float& ldsum) {
  const float xc = fminf(fmaxf(x, -TB), TB);

  // ---- widths: softmax (no max-sub: N(0,1) inputs, validated R5-R10) ----
  float uw[KBINS];
  extractAbs<LI * PPL, KBINS>(ch, uw);
  float s = 0.0f;
#pragma unroll
  for (int k = 0; k < KBINS; ++k) { uw[k] = __expf(uw[k]); s += uw[k]; }
  const float csw = (1.0f - KBINS * MIN_W) / s;

  float cum = 0.0f, ek = -TB;
  float xk = -TB, xk1 = TB;
  int idx = 0;
#pragma unroll
  for (int k = 0; k < KBINS; ++k) {
    cum += fmaf(uw[k], csw, MIN_W);
    const float ek1 = (k == KBINS - 1) ? TB : fmaf(2.0f * TB, cum, -TB);
    if (xc >= ek) { idx = k; xk = ek; xk1 = ek1; }
    ek = ek1;
  }
  const float wk = xk1 - xk;

  // ---- heights: softmax -> y edges, gather at idx ----
  float uh[KBINS];
  extractAbs<LI * PPL + KBINS, KBINS>(ch, uh);
  s = 0.0f;
#pragma unroll
  for (int k = 0; k < KBINS; ++k) { uh[k] = __expf(uh[k]); s += uh[k]; }
  const float csh = (1.0f - KBINS * MIN_H) / s;

  cum = 0.0f; ek = -TB;
  float yk = -TB, yk1 = TB;
#pragma unroll
  for (int k = 0; k < KBINS; ++k) {
    cum += fmaf(uh[k], csh, MIN_H);
    const float ek1 = (k == KBINS - 1) ? TB : fmaf(2.0f * TB, cum, -TB);
    if (k == idx) { yk = ek; yk1 = ek1; }
    ek = ek1;
  }
  const float hk = yk1 - yk;

  // ---- derivatives: only the two needed; pad -> 1.0 at the ends ----
  float ud[KBINS - 1];
  extractAbs<LI * PPL + 2 * KBINS, KBINS - 1>(ch, ud);
  float udk = 0.0f, udk1 = 0.0f;
#pragma unroll
  for (int j = 0; j < KBINS - 1; ++j) {
    if (j == idx - 1) udk  = ud[j];
    if (j == idx)     udk1 = ud[j];
  }
  const float dk  = (idx == 0)         ? 1.0f : MIN_D + softplusf(udk);
  const float dk1 = (idx == KBINS - 1) ? 1.0f : MIN_D + softplusf(udk1);

  // ---- rational-quadratic spline (forward) ----
  const float rw    = 1.0f / wk;
  const float delta = hk * rw;
  const float theta = (xc - xk) * rw;
  const float omt   = 1.0f - theta;
  const float t1m   = theta * omt;
  const float denom = delta + (dk + dk1 - 2.0f * delta) * t1m;
  const float y     = yk + hk * (delta * theta * theta + dk * t1m) / denom;
  const float dnum  = (delta * delta) *
                      (dk1 * theta * theta + 2.0f * delta * t1m + dk * omt * omt);
  const float ld    = __logf(dnum) - 2.0f * __logf(denom);

  const bool inside = (x >= -TB) && (x <= TB);
  x      = inside ? y : x;
  ldsum += inside ? ld : 0.0f;
}

// R8 structure with the burst SPLIT 36+11 to cut peak register pressure:
// chunks 0..35 (layers 0-2) issued up front; layer 3's chunks 36..46 issued
// right after layer-0 compute (still ~900 instrs ahead of consumption, deep
// prefetch), pinned with sched_barrier so the compiler can't re-hoist them.
// Peak live ~= 36 f4 + working (~195 VGPR) vs R8's ~240 -> no-spill margin,
// while queue depth stays ~R8. Single-variable spill test.
__global__ __launch_bounds__(256, 2) void nsf_flow_split(
    const float* __restrict__ params, const float* __restrict__ xin,
    float* __restrict__ yout, float* __restrict__ logdet, int epb) {
  const int e = blockIdx.x * 256 + threadIdx.x;   // grid sized exactly
  const float4* p4 = reinterpret_cast<const float4*>(params) + (size_t)e * REC_F4;

  float x = xin[e];
  __builtin_amdgcn_sched_barrier(0);

  float4 ch[REC_F4];
#pragma unroll
  for (int j = 0; j < 36; ++j) ch[j] = p4[j];     // burst A: layers 0-2

  float ldsum = 0.0f;
  computeLayer<0>(ch, x, ldsum);

  __builtin_amdgcn_sched_barrier(0);              // pin burst B below L0
#pragma unroll
  for (int j = 36; j < REC_F4; ++j) ch[j] = p4[j]; // burst B: layer 3
  __builtin_amdgcn_sched_barrier(0);

  computeLayer<1>(ch, x, ldsum);
  computeLayer<2>(ch, x, ldsum);
  computeLayer<3>(ch, x, ldsum);

  yout[e] = x;

  // ---- logdet: wave reduce -> LDS -> one atomic per block ----
  float v = ldsum;
#pragma unroll
  for (int o = 32; o > 0; o >>= 1) v += __shfl_xor(v, o, 64);
  __shared__ float red[4];
  const int wid = threadIdx.x >> 6;
  if ((threadIdx.x & 63) == 0) red[wid] = v;
  __syncthreads();
  if (threadIdx.x == 0) {
    const int b = e / epb;      // whole block lies in one batch (epb % 256 == 0)
    atomicAdd(&logdet[b], red[0] + red[1] + red[2] + red[3]);
  }
}

extern "C" void kernel_launch(void* const* d_in, const int* in_sizes, int n_in,
                              void* d_out, int out_size, void* d_ws, size_t ws_size,
                              hipStream_t stream) {
  const float* params = (const float*)d_in[0];
  const float* x      = (const float*)d_in[1];
  const int n   = in_sizes[1];        // 524288 elements
  const int nb  = out_size - n;       // 32 batches
  const int epb = n / nb;             // 16384 elements per batch
  float* y      = (float*)d_out;
  float* logdet = y + n;

  hipMemsetAsync(logdet, 0, nb * sizeof(float), stream);
  nsf_flow_split<<<dim3(n / 256), dim3(256), 0, stream>>>(params, x, y, logdet, epb);
}